// Round 2
// baseline (754.847 us; speedup 1.0000x reference)
//
#include <hip/hip_runtime.h>
#include <math.h>

// Problem constants (from reference: B,N,G,H,D = 16,10000,100,128,2)
#define Bc 16
#define Nc 10000
#define Gc 100
#define Hc 128
#define GPAD 104        // 100 real groups + row 100 = all-ones (mean) + 3 pad
#define NW 314          // bitmask words per (b,g): 157 tiles * 2 words
#define NTILE 64
#define NTILES 157      // ceil(10000/64)
#define NSPLIT 32       // n-splits for k_agg grid

#define RSH 0.08838834764831845f   // 1/sqrt(128)
#define RS2 0.7071067811865476f    // 1/sqrt(2)

// ---------------------------------------------------------------------------
// Kernel 1: agg[b][g][h] = sum_n m[g][n]*emb[b][n][h]   (m = visited?1:mask,
//           and m is EXACTLY 0.0 or 1.0 since group_ninf_mask is {0,-inf}).
//           Row g==100 is all-ones -> sum of embeddings (mean*N).
//           Also packs visited bitmask (1 bit per (b,g,n)).
// Atomic-accumulated into zeroed scratch across NSPLIT n-range blocks.
// ---------------------------------------------------------------------------
__global__ __launch_bounds__(256, 2)
void k_agg(const float* __restrict__ emb, const float* __restrict__ mask,
           float* __restrict__ agg, unsigned* __restrict__ bmask) {
  __shared__ float se[NTILE][Hc];     // 32768 B, emb tile [n][h]
  __shared__ float mT[NTILE][108];    // 27648 B, mask tile transposed [n][g]
  const int b = blockIdx.x;
  const int s = blockIdx.y;
  const int t = threadIdx.x;
  const int tx = t & 15;              // h-oct index: h0 = 8*tx
  const int ty = t >> 4;              // 0..15
  const int h0 = tx * 8;
  int g0c[2];
  g0c[0] = 4 * ty;                    // 0..60
  g0c[1] = 4 * ty + 64;               // 64..124
  if (g0c[1] > 100) g0c[1] = 100;     // clamp: keeps LDS reads in-bounds; results discarded at flush

  float acc[2][4][8];
  #pragma unroll
  for (int p = 0; p < 2; ++p)
    #pragma unroll
    for (int a = 0; a < 4; ++a)
      #pragma unroll
      for (int c = 0; c < 8; ++c) acc[p][a][c] = 0.f;

  const float* eb = emb + (size_t)b * Nc * Hc;
  const float* mb = mask + (size_t)b * Gc * Nc;

  for (int tile = s; tile < NTILES; tile += NSPLIT) {
    const int n0 = tile * NTILE;
    int valid = Nc - n0; if (valid > NTILE) valid = NTILE;
    __syncthreads();  // protect LDS from previous iteration's readers
    // ---- stage emb tile (float4, coalesced; zero pad rows)
    {
      const float4* src = (const float4*)(eb + (size_t)n0 * Hc);
      float4* dst = (float4*)(&se[0][0]);
      const int validF4 = valid * (Hc / 4);
      #pragma unroll
      for (int k = 0; k < 8; ++k) {
        int idx = k * 256 + t;                 // < 2048
        float4 v = {0.f, 0.f, 0.f, 0.f};
        if (idx < validF4) v = src[idx];       // guard: no OOB read
        dst[idx] = v;
      }
    }
    // ---- stage mask tile transposed + converted (visited -> 1.0)
    #pragma unroll
    for (int k = 0; k < 26; ++k) {
      int lin = k * 256 + t;                   // < 6656 = 104*64
      int g = lin >> 6;
      int n = lin & 63;
      float m = 0.f;
      if (n < valid) {
        if (g < Gc) {
          float v = mb[(size_t)g * Nc + n0 + n];
          m = (v < -1e30f) ? 1.0f : v;         // where(isneginf, 1.0, mask)
        } else if (g == Gc) {
          m = 1.0f;                            // mean row
        }
      }
      mT[n][g] = m;
    }
    __syncthreads();
    // ---- pack visited bitmask: 2 words per (g, tile)
    if (t < 200) {
      int g = t >> 1, w = t & 1;
      unsigned bits = 0u;
      #pragma unroll
      for (int j = 0; j < 32; ++j)
        if (mT[w * 32 + j][g] != 0.f) bits |= (1u << j);
      bmask[((size_t)b * Gc + g) * NW + 2 * tile + w] = bits;
    }
    // ---- rank-1 accumulate: acc[p][g][h] += m[g,n]*e[n,h]
    #pragma unroll 2
    for (int n = 0; n < NTILE; ++n) {
      float4 e0 = *(const float4*)(&se[n][h0]);
      float4 e1 = *(const float4*)(&se[n][h0 + 4]);
      float ef[8] = {e0.x, e0.y, e0.z, e0.w, e1.x, e1.y, e1.z, e1.w};
      #pragma unroll
      for (int p = 0; p < 2; ++p) {
        float4 mv = *(const float4*)(&mT[n][g0c[p]]);
        float m4[4] = {mv.x, mv.y, mv.z, mv.w};
        #pragma unroll
        for (int a = 0; a < 4; ++a)
          #pragma unroll
          for (int c = 0; c < 8; ++c)
            acc[p][a][c] += m4[a] * ef[c];
      }
    }
  }
  // ---- flush (guard uses UNclamped g; clamped lanes have g>=104 -> skipped)
  #pragma unroll
  for (int p = 0; p < 2; ++p) {
    #pragma unroll
    for (int a = 0; a < 4; ++a) {
      int g = 4 * ty + 64 * p + a;
      if (g < GPAD) {
        #pragma unroll
        for (int c = 0; c < 8; ++c)
          atomicAdd(&agg[((size_t)b * GPAD + g) * Hc + h0 + c], acc[p][a][c]);
      }
    }
  }
}

// ---------------------------------------------------------------------------
// Kernel 2: final_q[row][o] = sum over 384-concat of
//   [last_emb | agg/N | mean/N] . [Wl+Wf | Wv | Wg]^T      (row = b*100+g)
// Also gathers last-node coordinates -> lastc[row][2].
// ---------------------------------------------------------------------------
__global__ __launch_bounds__(256)
void k_fq(const float* __restrict__ emb, const float* __restrict__ coords,
          const int* __restrict__ last, const float* __restrict__ Wg,
          const float* __restrict__ Wf, const float* __restrict__ Wl,
          const float* __restrict__ Wv, const float* __restrict__ agg,
          float* __restrict__ fq, float* __restrict__ lastc) {
  __shared__ float xt[16][385];   // 16 rows x 384 cols, pad 385 (bank spread)
  __shared__ float wT[16][132];   // weight chunk transposed [j][o], pad 132
  __shared__ int ln_s[16];
  const int t = threadIdx.x;
  const int row0 = blockIdx.x * 16;

  if (t < 16) {
    int row = row0 + t;
    int b = row / Gc, g = row - b * Gc;
    ln_s[t] = last[b * Gc + g];
  }
  __syncthreads();
  const float invN = 1.0f / (float)Nc;
  #pragma unroll
  for (int k = 0; k < 24; ++k) {
    int lin = k * 256 + t;                 // < 6144 = 16*384
    int r = lin / 384, c = lin - r * 384;
    int row = row0 + r;
    int b = row / Gc, g = row - b * Gc;
    float v;
    if (c < 128)       v = emb[((size_t)b * Nc + ln_s[r]) * Hc + c];
    else if (c < 256)  v = agg[((size_t)b * GPAD + g) * Hc + (c - 128)] * invN;
    else               v = agg[((size_t)b * GPAD + Gc) * Hc + (c - 256)] * invN;
    xt[r][c] = v;
  }
  if (t < 32) {
    int r = t >> 1, d = t & 1;
    int row = row0 + r;
    int b = row / Gc;
    lastc[(size_t)row * 2 + d] = coords[((size_t)b * Nc + ln_s[r]) * 2 + d];
  }

  const int tx = t & 31, ty = t >> 5;      // cols c0=4*tx, rows r0=2*ty
  float acc[2][4] = {{0.f,0.f,0.f,0.f},{0.f,0.f,0.f,0.f}};
  for (int kc = 0; kc < 24; ++kc) {
    __syncthreads();
    {   // stage 16-col weight chunk, transposed; lane->col contiguous reads
      int j = t & 15, oo = t >> 4;         // oo 0..15
      int col = kc * 16 + j;
      #pragma unroll
      for (int i = 0; i < 8; ++i) {
        int o = i * 16 + oo;
        float w;
        if (col < 128)      w = Wl[o * Hc + col] + Wf[o * Hc + col];
        else if (col < 256) w = Wv[o * Hc + (col - 128)];
        else                w = Wg[o * Hc + (col - 256)];
        wT[j][o] = w;
      }
    }
    __syncthreads();
    #pragma unroll
    for (int j = 0; j < 16; ++j) {
      int col = kc * 16 + j;
      float x0 = xt[2 * ty][col];
      float x1 = xt[2 * ty + 1][col];
      float4 w = *(const float4*)(&wT[j][4 * tx]);
      float w4[4] = {w.x, w.y, w.z, w.w};
      #pragma unroll
      for (int cc = 0; cc < 4; ++cc) {
        acc[0][cc] += x0 * w4[cc];
        acc[1][cc] += x1 * w4[cc];
      }
    }
  }
  #pragma unroll
  for (int rr = 0; rr < 2; ++rr) {
    int row = row0 + 2 * ty + rr;
    #pragma unroll
    for (int cc = 0; cc < 4; ++cc)
      fq[(size_t)row * Hc + 4 * tx + cc] = acc[rr][cc];
  }
}

// ---------------------------------------------------------------------------
// Kernel 3: score GEMM + dist + 10*tanh + masked exp. Writes unnormalized
// e = exp(clipped) (0 where visited) to out; atomically accumulates row sums.
// No max pass needed: clipped in [-10,10] by construction.
// eT is XOR-swizzled: element (h,n) lives at eT[h][n ^ (8*(h&7))].
//   write bank = (4h + n^8(h&7)) mod 32 -> 8 distinct per 8-h group (free);
//   read quad at col 4*(tx^2c) (c=h&7) returns original n=4tx..4tx+3 in order.
// Block = (tile of 64 n) x (half of groups: 50) x b.
// ---------------------------------------------------------------------------
__global__ __launch_bounds__(256, 2)
void k_score(const float* __restrict__ emb, const float* __restrict__ coords,
             const float* __restrict__ fq, const float* __restrict__ lastc,
             const unsigned* __restrict__ bmask, float* __restrict__ sums,
             float* __restrict__ out) {
  __shared__ float q_l[52][130];      // 27040 B (50 q rows + 2 zero rows)
  __shared__ float eT[Hc][68];        // 34816 B emb tile transposed+swizzled
  __shared__ float cxs[NTILE], cys[NTILE];
  __shared__ float lcx[52], lcy[52];
  __shared__ unsigned bm[52][2];
  const int tile = blockIdx.x;        // 0..156
  const int gh = blockIdx.y;          // 0..1  (g offset gh*50)
  const int b = blockIdx.z;           // 0..15
  const int t = threadIdx.x;
  const int n0 = tile * NTILE;
  int valid = Nc - n0; if (valid > NTILE) valid = NTILE;

  // stage q (rows 50,51 zero)
  #pragma unroll
  for (int k = 0; k < 26; ++k) {
    int lin = k * 256 + t;            // < 6656 = 52*128
    int g = lin >> 7, h = lin & 127;
    float v = 0.f;
    if (g < 50) v = fq[((size_t)b * Gc + gh * 50 + g) * Hc + h];
    q_l[g][h] = v;
  }
  // stage emb tile transposed, XOR-swizzled columns
  {
    const float* ebp = emb + ((size_t)b * Nc + n0) * Hc;
    #pragma unroll
    for (int k = 0; k < 32; ++k) {
      int lin = k * 256 + t;          // < 8192
      int n = lin >> 7, h = lin & 127;
      int col = n ^ (8 * (h & 7));    // swizzle (bits 3-5 of n)
      eT[h][col] = (n < valid) ? ebp[lin] : 0.f;
    }
  }
  if (t < NTILE) {
    float vx = 0.f, vy = 0.f;
    if (t < valid) {
      vx = coords[((size_t)b * Nc + n0 + t) * 2 + 0];
      vy = coords[((size_t)b * Nc + n0 + t) * 2 + 1];
    }
    cxs[t] = vx; cys[t] = vy;
  }
  if (t < 104) {
    int g = t >> 1, d = t & 1;
    float v = 0.f;
    if (g < 50) v = lastc[((size_t)b * Gc + gh * 50 + g) * 2 + d];
    if (d == 0) lcx[g] = v; else lcy[g] = v;
  }
  if (t >= 104 && t < 208) {
    int u = t - 104;
    int g = u >> 1, w = u & 1;
    unsigned bits = 0u;
    if (g < 50) bits = bmask[((size_t)b * Gc + gh * 50 + g) * NW + 2 * tile + w];
    bm[g][w] = bits;
  }
  __syncthreads();

  const int tx = t & 15, ty = t >> 4;    // n = 4*tx+j ; g = ty + 16*i
  const float* qr[4];
  #pragma unroll
  for (int i = 0; i < 4; ++i) {
    int g = ty + 16 * i; if (g > 51) g = 51;   // clamped rows are zero -> acc 0
    qr[i] = &q_l[g][0];
  }
  // swizzled read column bases: for row h (c=h&7) quad starts at 4*(tx^2c)
  int offs[8];
  #pragma unroll
  for (int c = 0; c < 8; ++c) offs[c] = 4 * (tx ^ (2 * c));

  float acc[4][4];
  #pragma unroll
  for (int i = 0; i < 4; ++i)
    #pragma unroll
    for (int j = 0; j < 4; ++j) acc[i][j] = 0.f;

  for (int hb = 0; hb < Hc; hb += 8) {
    #pragma unroll
    for (int c = 0; c < 8; c += 2) {     // h&7 == c is a compile-time constant
      const int h = hb + c;
      float4 ea  = *(const float4*)(&eT[h][offs[c]]);
      float4 ebv = *(const float4*)(&eT[h + 1][offs[c + 1]]);
      float e0[4] = {ea.x, ea.y, ea.z, ea.w};
      float e1[4] = {ebv.x, ebv.y, ebv.z, ebv.w};
      #pragma unroll
      for (int i = 0; i < 4; ++i) {
        float2 qv = *(const float2*)(qr[i] + h);
        #pragma unroll
        for (int j = 0; j < 4; ++j)
          acc[i][j] += qv.x * e0[j] + qv.y * e1[j];
      }
    }
  }
  __syncthreads();                 // everyone done reading q_l; reuse it as e-buffer
  float* ew = &q_l[0][0];          // rows stride 65; max idx 63*65+63 < 6760 OK

  #pragma unroll
  for (int i = 0; i < 4; ++i) {
    int g = ty + 16 * i;
    bool gv = (g < 50);
    int gc = g > 51 ? 51 : g;
    float lx = lcx[gc], ly = lcy[gc];
    unsigned b0 = bm[gc][0], b1 = bm[gc][1];
    float ps = 0.f;
    #pragma unroll
    for (int j = 0; j < 4; ++j) {
      int n = 4 * tx + j;
      float dx = lx - cxs[n], dy = ly - cys[n];
      float dist = sqrtf(fmaxf(dx * dx + dy * dy, 1e-12f));
      float sc = acc[i][j] * RSH - dist * RS2;
      sc = fminf(fmaxf(sc, -15.f), 15.f);          // tanh saturated beyond
      float ex2 = __expf(2.f * sc);
      float th = (ex2 - 1.f) / (ex2 + 1.f);        // tanh(sc)
      float logit = 10.f * th;                     // in [-10,10] -> exp safe
      unsigned wb = (n < 32) ? b0 : b1;
      bool vis = ((wb >> (n & 31)) & 1u) != 0u;
      float e = (gv && !vis && (n0 + n) < Nc) ? __expf(logit) : 0.f;
      ps += e;
      ew[g * 65 + n] = e;                          // conflict-free (bank=g+4tx+j)
    }
    #pragma unroll
    for (int m = 8; m >= 1; m >>= 1) ps += __shfl_xor(ps, m, 64);
    if (tx == 0 && gv) atomicAdd(&sums[b * Gc + gh * 50 + g], ps);
  }
  __syncthreads();
  // float4 store of the 50x64 e-tile (row base n0*4B is 16B-aligned)
  #pragma unroll
  for (int k = 0; k < 4; ++k) {
    int lin4 = k * 256 + t;
    if (lin4 < 800) {                  // 800 = 50 g * 16 quads
      int g = lin4 >> 4, n = (lin4 & 15) * 4;
      if (n0 + n < Nc) {               // quad fully valid (all mult-of-4)
        float4 v;
        v.x = ew[g * 65 + n + 0];
        v.y = ew[g * 65 + n + 1];
        v.z = ew[g * 65 + n + 2];
        v.w = ew[g * 65 + n + 3];
        *(float4*)(&out[((size_t)b * Gc + gh * 50 + g) * Nc + n0 + n]) = v;
      }
    }
  }
}

// ---------------------------------------------------------------------------
// Kernel 4: probs = e / rowsum   (float4; 10000 % 4 == 0 so rows are f4-aligned)
// ---------------------------------------------------------------------------
__global__ __launch_bounds__(256)
void k_norm(float* __restrict__ out, const float* __restrict__ sums) {
  const int i = blockIdx.x * 256 + threadIdx.x;   // < 4,000,000 exactly
  float4* o4 = (float4*)out;
  int row = i / 2500;                             // N/4 f4 per row
  float inv = 1.0f / sums[row];
  float4 v = o4[i];
  v.x *= inv; v.y *= inv; v.z *= inv; v.w *= inv;
  o4[i] = v;
}

// ---------------------------------------------------------------------------
extern "C" void kernel_launch(void* const* d_in, const int* in_sizes, int n_in,
                              void* d_out, int out_size, void* d_ws, size_t ws_size,
                              hipStream_t stream) {
  const float* emb    = (const float*)d_in[0];
  const float* coords = (const float*)d_in[1];
  const int*   last   = (const int*)d_in[2];
  const float* mask   = (const float*)d_in[3];
  const float* Wg     = (const float*)d_in[4];
  const float* Wf     = (const float*)d_in[5];
  const float* Wl     = (const float*)d_in[6];
  const float* Wv     = (const float*)d_in[7];
  // d_in[8] = S (step index) -- unused by the computation
  float* out = (float*)d_out;

  // workspace layout (floats): agg | sums | fq | lastc | bmask  (~3.7 MB)
  float* agg   = (float*)d_ws;                           // [B][GPAD][H]
  float* sums  = agg + (size_t)Bc * GPAD * Hc;           // [B][G]
  float* fq    = sums + Bc * Gc;                         // [B][G][H]
  float* lastc = fq + (size_t)Bc * Gc * Hc;              // [B][G][2]
  unsigned* bmask = (unsigned*)(lastc + (size_t)Bc * Gc * 2);  // [B][G][NW]

  // zero the atomic accumulators (agg + sums)
  size_t zeroBytes = ((size_t)Bc * GPAD * Hc + (size_t)Bc * Gc) * sizeof(float);
  hipMemsetAsync(d_ws, 0, zeroBytes, stream);

  k_agg  <<<dim3(Bc, NSPLIT), 256, 0, stream>>>(emb, mask, agg, bmask);
  k_fq   <<<dim3(100),        256, 0, stream>>>(emb, coords, last, Wg, Wf, Wl, Wv,
                                                agg, fq, lastc);
  k_score<<<dim3(NTILES, 2, Bc), 256, 0, stream>>>(emb, coords, fq, lastc, bmask,
                                                   sums, out);
  k_norm <<<dim3(15625),      256, 0, stream>>>(out, sums);
}

// Round 7
// 618.104 us; speedup vs baseline: 1.2212x; 1.2212x over previous
//
#include <hip/hip_runtime.h>
#include <math.h>

// Problem constants (B,N,G,H,D = 16,10000,100,128,2)
#define Bc 16
#define Nc 10000
#define Gc 100
#define GR 104          // 100 groups + row 100 = mean row + pad to 104
#define Hc 128
#define NTILE 64
#define NTILES 157      // ceil(10000/64)
#define NSPLIT 32       // k_agg K-splits
#define SSPLIT 16       // k_score tile-splits
#define NWQ 157         // bitmask: one 64-bit word per (b,g,tile)

#define RSH 0.08838834764831845f   // 1/sqrt(128)
#define RS2 0.7071067811865476f    // 1/sqrt(2)

typedef short bf16x8 __attribute__((ext_vector_type(8)));   // 8 bf16 (4 VGPR)
typedef float f32x16 __attribute__((ext_vector_type(16)));  // 32x32 acc

__device__ __forceinline__ unsigned short bf16_rne(float f) {
  unsigned u = __float_as_uint(f);
  return (unsigned short)((u + 0x7FFF + ((u >> 16) & 1)) >> 16);
}

// ---------------------------------------------------------------------------
// k_agg (MFMA): agg[b][g][h] = sum_n m[g][n]*emb[b][n][h], m in {0,1} exactly.
// A = mask tile [128 g][64 n] bf16 (rows 104..127 zero), B = embT hi/lo
// [128 h][64 n] bf16. v_mfma_f32_32x32x16_bf16, 2 MFMA (hi+lo) per B tile.
// A/B k-grouping note: both fragments use the same assumed (lane,reg)->k map,
// so any permutation error cancels (dot product invariant); row/col = lane&31
// is pinned by the HW-verified C/D layout.
// LDS layout granule-swizzled: elem n of row r stored at
//   idx = r*64 + ((n&7) | (((n>>3) ^ (r&7)) << 3))
// K-split over NSPLIT blocks; flush = partial buffer (if ws fits) or atomics.
// Also packs visited bitmask via wave ballot (lanes==n, wave-uniform g).
// ---------------------------------------------------------------------------
__global__ __launch_bounds__(512, 2)
void k_agg(const float* __restrict__ emb, const float* __restrict__ mask,
           float* __restrict__ agg, float* __restrict__ part,
           unsigned long long* __restrict__ bmq, int useAtomic) {
  __shared__ unsigned short Am[128 * 64];   // 16 KB
  __shared__ unsigned short Bh[128 * 64];   // 16 KB
  __shared__ unsigned short Bl[128 * 64];   // 16 KB
  const int b = blockIdx.x, s = blockIdx.y, t = threadIdx.x;
  const int w = t >> 6, l = t & 63;
  const int rowblk = w & 3;       // g block: rows rowblk*32..+31
  const int colpair = w >> 2;     // h blocks: colpair*64 .. +63 (two 32-col tiles)

  // zero pad rows 104..127 of Am once (24 rows * 64 shorts = 768 ints)
  if (t < 768) ((int*)&Am[104 * 64])[t] = 0;

  f32x16 acc0, acc1;
  #pragma unroll
  for (int i = 0; i < 16; ++i) { acc0[i] = 0.f; acc1[i] = 0.f; }

  const float* eb = emb + (size_t)b * Nc * Hc;
  const float* mb = mask + (size_t)b * Gc * Nc;

  for (int tile = s; tile < NTILES; tile += NSPLIT) {
    const int n0 = tile * NTILE;
    const int valid = min(NTILE, Nc - n0);
    __syncthreads();
    // ---- stage mask: iter k -> wave-uniform g = k*8 + w; lanes = n
    #pragma unroll
    for (int k = 0; k < 13; ++k) {
      int g = k * 8 + w;                   // 0..103, each exactly once
      int n = l;
      float m = 0.f;
      if (g < Gc) {
        if (n < valid) {
          float v = mb[(size_t)g * Nc + n0 + n];
          m = (v < -1e30f) ? 1.0f : v;     // where(isneginf,1,mask); v in {0,-inf}
        }
        unsigned long long bits = __ballot(m != 0.f);
        if (l == 0) bmq[((size_t)b * Gc + g) * NWQ + tile] = bits;
      } else if (g == Gc) {
        m = (n < valid) ? 1.0f : 0.f;      // mean row (all ones)
      }
      int p = (n & 7) | ((((n >> 3) ^ (g & 7))) << 3);
      Am[g * 64 + p] = bf16_rne(m);
    }
    // ---- stage emb transposed hi/lo, pair-packed ushort2 stores
    #pragma unroll
    for (int k = 0; k < 8; ++k) {
      int lin = k * 512 + t;               // < 4096 = 32 n-pairs * 128 h
      int n2 = lin >> 7, h = lin & 127;
      int n = 2 * n2;
      float v0 = 0.f, v1 = 0.f;
      if (n < valid)     v0 = eb[(size_t)(n0 + n) * Hc + h];
      if (n + 1 < valid) v1 = eb[(size_t)(n0 + n + 1) * Hc + h];
      unsigned short h0 = bf16_rne(v0), h1 = bf16_rne(v1);
      float r0 = v0 - __uint_as_float((unsigned)h0 << 16);
      float r1 = v1 - __uint_as_float((unsigned)h1 << 16);
      unsigned short l0 = bf16_rne(r0), l1 = bf16_rne(r1);
      int p = (n & 7) | ((((n >> 3) ^ (h & 7))) << 3);   // n even -> p even
      *(ushort2*)&Bh[h * 64 + p] = make_ushort2(h0, h1);
      *(ushort2*)&Bl[h * 64 + p] = make_ushort2(l0, l1);
    }
    __syncthreads();
    // ---- 4 K-steps of 16, 2 col-tiles, hi+lo
    #pragma unroll
    for (int ks = 0; ks < 4; ++ks) {
      const int n8 = ks * 16 + (l >> 5) * 8;      // 8 consecutive n per lane
      const int ga = rowblk * 32 + (l & 31);
      const int h0a = colpair * 64 + (l & 31);
      const int h1a = h0a + 32;
      bf16x8 af  = *(const bf16x8*)&Am[ga * 64 + (((n8 >> 3) ^ (ga & 7)) << 3)];
      bf16x8 bh0 = *(const bf16x8*)&Bh[h0a * 64 + (((n8 >> 3) ^ (h0a & 7)) << 3)];
      bf16x8 bl0 = *(const bf16x8*)&Bl[h0a * 64 + (((n8 >> 3) ^ (h0a & 7)) << 3)];
      bf16x8 bh1 = *(const bf16x8*)&Bh[h1a * 64 + (((n8 >> 3) ^ (h1a & 7)) << 3)];
      bf16x8 bl1 = *(const bf16x8*)&Bl[h1a * 64 + (((n8 >> 3) ^ (h1a & 7)) << 3)];
      acc0 = __builtin_amdgcn_mfma_f32_32x32x16_bf16(af, bh0, acc0, 0, 0, 0);
      acc0 = __builtin_amdgcn_mfma_f32_32x32x16_bf16(af, bl0, acc0, 0, 0, 0);
      acc1 = __builtin_amdgcn_mfma_f32_32x32x16_bf16(af, bh1, acc1, 0, 0, 0);
      acc1 = __builtin_amdgcn_mfma_f32_32x32x16_bf16(af, bl1, acc1, 0, 0, 0);
    }
  }
  // ---- flush: C/D layout (verified): col=lane&31, row=(r&3)+8*(r>>2)+4*(lane>>5)
  const int gbase = rowblk * 32;
  const int h0a = colpair * 64 + (l & 31);
  #pragma unroll
  for (int r = 0; r < 16; ++r) {
    int g = gbase + (r & 3) + 8 * (r >> 2) + 4 * (l >> 5);
    if (g < GR) {
      if (useAtomic) {
        atomicAdd(&agg[((size_t)b * GR + g) * Hc + h0a],      acc0[r]);
        atomicAdd(&agg[((size_t)b * GR + g) * Hc + h0a + 32], acc1[r]);
      } else {
        float* pp = part + (((size_t)s * Bc + b) * GR + g) * Hc;
        pp[h0a]      = acc0[r];
        pp[h0a + 32] = acc1[r];
      }
    }
  }
}

// ---------------------------------------------------------------------------
// k_red: agg[o] = sum_s part[s][o]   (o = (b,g,h), 212992 elems, 832 blocks)
// ---------------------------------------------------------------------------
__global__ __launch_bounds__(256)
void k_red(const float* __restrict__ part, float* __restrict__ agg) {
  const int o = blockIdx.x * 256 + threadIdx.x;   // grid sized exactly
  float sum = 0.f;
  #pragma unroll
  for (int s = 0; s < NSPLIT; ++s)
    sum += part[(size_t)s * Bc * GR * Hc + o];
  agg[o] = sum;
}

// ---------------------------------------------------------------------------
// k_fq: final_q[row][o] = [last_emb | agg/N | mean/N] . [Wl+Wf | Wv | Wg]^T
// ---------------------------------------------------------------------------
__global__ __launch_bounds__(256)
void k_fq(const float* __restrict__ emb, const float* __restrict__ coords,
          const int* __restrict__ last, const float* __restrict__ Wg,
          const float* __restrict__ Wf, const float* __restrict__ Wl,
          const float* __restrict__ Wv, const float* __restrict__ agg,
          float* __restrict__ fq, float* __restrict__ lastc) {
  __shared__ float xt[16][385];
  __shared__ float wT[16][132];
  __shared__ int ln_s[16];
  const int t = threadIdx.x;
  const int row0 = blockIdx.x * 16;

  if (t < 16) {
    int row = row0 + t;
    int b = row / Gc, g = row - b * Gc;
    ln_s[t] = last[b * Gc + g];
  }
  __syncthreads();
  const float invN = 1.0f / (float)Nc;
  #pragma unroll
  for (int k = 0; k < 24; ++k) {
    int lin = k * 256 + t;                 // < 6144 = 16*384
    int r = lin / 384, c = lin - r * 384;
    int row = row0 + r;
    int b = row / Gc, g = row - b * Gc;
    float v;
    if (c < 128)       v = emb[((size_t)b * Nc + ln_s[r]) * Hc + c];
    else if (c < 256)  v = agg[((size_t)b * GR + g) * Hc + (c - 128)] * invN;
    else               v = agg[((size_t)b * GR + Gc) * Hc + (c - 256)] * invN;
    xt[r][c] = v;
  }
  if (t < 32) {
    int r = t >> 1, d = t & 1;
    int row = row0 + r;
    int b = row / Gc;
    lastc[(size_t)row * 2 + d] = coords[((size_t)b * Nc + ln_s[r]) * 2 + d];
  }

  const int tx = t & 31, ty = t >> 5;
  float acc[2][4] = {{0.f,0.f,0.f,0.f},{0.f,0.f,0.f,0.f}};
  for (int kc = 0; kc < 24; ++kc) {
    __syncthreads();
    {   // stage 16-col weight chunk transposed; lane->col contiguous reads
      int j = t & 15, oo = t >> 4;
      int col = kc * 16 + j;
      #pragma unroll
      for (int i = 0; i < 8; ++i) {
        int o = i * 16 + oo;
        float wv;
        if (col < 128)      wv = Wl[o * Hc + col] + Wf[o * Hc + col];
        else if (col < 256) wv = Wv[o * Hc + (col - 128)];
        else                wv = Wg[o * Hc + (col - 256)];
        wT[j][o] = wv;
      }
    }
    __syncthreads();
    #pragma unroll
    for (int j = 0; j < 16; ++j) {
      int col = kc * 16 + j;
      float x0 = xt[2 * ty][col];
      float x1 = xt[2 * ty + 1][col];
      float4 wv = *(const float4*)(&wT[j][4 * tx]);
      float w4[4] = {wv.x, wv.y, wv.z, wv.w};
      #pragma unroll
      for (int cc = 0; cc < 4; ++cc) {
        acc[0][cc] += x0 * w4[cc];
        acc[1][cc] += x1 * w4[cc];
      }
    }
  }
  #pragma unroll
  for (int rr = 0; rr < 2; ++rr) {
    int row = row0 + 2 * ty + rr;
    #pragma unroll
    for (int cc = 0; cc < 4; ++cc)
      fq[(size_t)row * Hc + 4 * tx + cc] = acc[rr][cc];
  }
}

// ---------------------------------------------------------------------------
// k_score: per block (split,gh,b): q staged ONCE, loop over 10 n-tiles.
// fp32 FMA core (validated round 2); e stored directly from registers
// (coalesced float2), row-sums accumulated in registers, flushed once.
// ---------------------------------------------------------------------------
__global__ __launch_bounds__(512, 4)
void k_score(const float* __restrict__ emb, const float* __restrict__ coords,
             const float* __restrict__ fq, const float* __restrict__ lastc,
             const unsigned* __restrict__ bmw, float* __restrict__ sums,
             float* __restrict__ out) {
  __shared__ float q_l[52][130];      // 27040 B (50 rows + 2 zero rows)
  __shared__ float eT[Hc][68];        // 34816 B, swizzled: elem n at col n^(8*(h&7))
  __shared__ float cxs[NTILE], cys[NTILE];
  __shared__ float lcx[52], lcy[52];
  __shared__ unsigned bmt[104];       // 2 words per local g (50 used)
  const int s2 = blockIdx.x;          // 0..15
  const int gh = blockIdx.y;          // 0..1
  const int b  = blockIdx.z;          // 0..15
  const int t = threadIdx.x;
  const int tx = t & 31;              // n pair: n = 2*tx + j
  const int ty = t >> 5;              // 0..15 : g = ty + 16*i
  const int l  = t & 63;

  // ---- stage q once (rows 50,51 zero)
  #pragma unroll
  for (int k = 0; k < 13; ++k) {
    int lin = k * 512 + t;            // < 6656 = 52*128
    int g = lin >> 7, h = lin & 127;
    float v = 0.f;
    if (g < 50) v = fq[((size_t)b * Gc + gh * 50 + g) * Hc + h];
    q_l[g][h] = v;
  }
  if (t < 104) {
    int g = t >> 1, d = t & 1;
    float v = 0.f;
    if (g < 50) v = lastc[((size_t)b * Gc + gh * 50 + g) * 2 + d];
    if (d == 0) lcx[g] = v; else lcy[g] = v;
  }
  const float* qr[4];
  #pragma unroll
  for (int i = 0; i < 4; ++i) {
    int g = ty + 16 * i; if (g > 51) g = 51;
    qr[i] = &q_l[g][0];
  }
  float rs[4] = {0.f, 0.f, 0.f, 0.f};

  for (int tile = s2; tile < NTILES; tile += SSPLIT) {
    const int n0 = tile * NTILE;
    const int valid = min(NTILE, Nc - n0);
    __syncthreads();                  // protect eT/cxs/bmt (and 1st-iter q_l)
    {   // stage emb tile transposed+swizzled
      const float* ebp = emb + ((size_t)b * Nc + n0) * Hc;
      #pragma unroll
      for (int k = 0; k < 16; ++k) {
        int lin = k * 512 + t;        // < 8192
        int n = lin >> 7, h = lin & 127;
        int col = n ^ (8 * (h & 7));
        eT[h][col] = (n < valid) ? ebp[lin] : 0.f;
      }
    }
    if (t < NTILE) {
      float vx = 0.f, vy = 0.f;
      if (t < valid) {
        vx = coords[((size_t)b * Nc + n0 + t) * 2 + 0];
        vy = coords[((size_t)b * Nc + n0 + t) * 2 + 1];
      }
      cxs[t] = vx; cys[t] = vy;
    }
    if (t < 100) {
      int g = t >> 1, ww = t & 1;
      bmt[t] = bmw[(((size_t)b * Gc + gh * 50 + g) * NWQ + tile) * 2 + ww];
    }
    __syncthreads();

    float acc[4][2];
    #pragma unroll
    for (int i = 0; i < 4; ++i) { acc[i][0] = 0.f; acc[i][1] = 0.f; }

    for (int hb = 0; hb < Hc; hb += 8) {
      #pragma unroll
      for (int c = 0; c < 8; c += 2) {      // h&7 == c : compile-time swizzle
        const int h = hb + c;
        float2 ea  = *(const float2*)(&eT[h][(2 * tx) ^ (8 * c)]);
        float2 eb2 = *(const float2*)(&eT[h + 1][(2 * tx) ^ (8 * (c + 1))]);
        #pragma unroll
        for (int i = 0; i < 4; ++i) {
          float2 qv = *(const float2*)(qr[i] + h);
          acc[i][0] += qv.x * ea.x + qv.y * eb2.x;
          acc[i][1] += qv.x * ea.y + qv.y * eb2.y;
        }
      }
    }

    #pragma unroll
    for (int i = 0; i < 4; ++i) {
      int g = ty + 16 * i;
      bool gv = (g < 50);
      int gc = g > 51 ? 51 : g;
      float lx = lcx[gc], ly = lcy[gc];
      unsigned bb0 = gv ? bmt[2 * gc] : 0u, bb1 = gv ? bmt[2 * gc + 1] : 0u;
      float ps = 0.f;
      float ev0 = 0.f, ev1 = 0.f;
      #pragma unroll
      for (int j = 0; j < 2; ++j) {
        int n = 2 * tx + j;
        float dx = lx - cxs[n], dy = ly - cys[n];
        float dist = sqrtf(fmaxf(dx * dx + dy * dy, 1e-12f));
        float sc = acc[i][j] * RSH - dist * RS2;
        sc = fminf(fmaxf(sc, -15.f), 15.f);
        float ex2 = __expf(2.f * sc);
        float th = (ex2 - 1.f) / (ex2 + 1.f);       // tanh
        float logit = 10.f * th;                    // in [-10,10]: exp safe
        unsigned wb = (n < 32) ? bb0 : bb1;
        bool vis = ((wb >> (n & 31)) & 1u) != 0u;
        float e = (gv && !vis && (n0 + n) < Nc) ? __expf(logit) : 0.f;
        ps += e;
        if (j == 0) ev0 = e; else ev1 = e;
      }
      if (gv && 2 * tx < valid)   // valid is even: pair never straddles
        *(float2*)&out[((size_t)b * Gc + gh * 50 + g) * Nc + n0 + 2 * tx] =
            make_float2(ev0, ev1);
      #pragma unroll
      for (int m = 1; m <= 16; m <<= 1) ps += __shfl_xor(ps, m, 64);
      rs[i] += ps;                  // 32-lane halves reduce independently
    }
  }
  #pragma unroll
  for (int i = 0; i < 4; ++i) {
    int g = ty + 16 * i;
    if ((l & 31) == 0 && g < 50)
      atomicAdd(&sums[b * Gc + gh * 50 + g], rs[i]);
  }
}

// ---------------------------------------------------------------------------
// k_norm: probs = e / rowsum
// ---------------------------------------------------------------------------
__global__ __launch_bounds__(256)
void k_norm(float* __restrict__ out, const float* __restrict__ sums) {
  const int i = blockIdx.x * 256 + threadIdx.x;   // < 4,000,000 exactly
  float4* o4 = (float4*)out;
  int row = i / 2500;
  float inv = 1.0f / sums[row];
  float4 v = o4[i];
  v.x *= inv; v.y *= inv; v.z *= inv; v.w *= inv;
  o4[i] = v;
}

// ---------------------------------------------------------------------------
extern "C" void kernel_launch(void* const* d_in, const int* in_sizes, int n_in,
                              void* d_out, int out_size, void* d_ws, size_t ws_size,
                              hipStream_t stream) {
  const float* emb    = (const float*)d_in[0];
  const float* coords = (const float*)d_in[1];
  const int*   last   = (const int*)d_in[2];
  const float* mask   = (const float*)d_in[3];
  const float* Wg     = (const float*)d_in[4];
  const float* Wf     = (const float*)d_in[5];
  const float* Wl     = (const float*)d_in[6];
  const float* Wv     = (const float*)d_in[7];
  float* out = (float*)d_out;

  // ws layout (floats): agg[16*104*128] | sums[1600] | fq[204800] | lastc[3200]
  //                     | bmq (ull, 16*100*157) | part (optional)
  float* agg   = (float*)d_ws;
  float* sums  = agg + (size_t)Bc * GR * Hc;            // 212992
  float* fq    = sums + Bc * Gc;                        // +1600
  float* lastc = fq + (size_t)Bc * Gc * Hc;             // +204800
  unsigned long long* bmq = (unsigned long long*)(lastc + (size_t)Bc * Gc * 2);
  float* part = (float*)(bmq + (size_t)Bc * Gc * NWQ);
  size_t baseBytes = (size_t)((char*)part - (char*)d_ws);
  size_t partBytes = (size_t)NSPLIT * Bc * GR * Hc * sizeof(float);
  int useAtomic = (baseBytes + partBytes > ws_size) ? 1 : 0;

  // zero atomic accumulators (agg + sums are contiguous)
  hipMemsetAsync(d_ws, 0, ((size_t)Bc * GR * Hc + Bc * Gc) * sizeof(float), stream);

  k_agg<<<dim3(Bc, NSPLIT), 512, 0, stream>>>(emb, mask, agg, part, bmq, useAtomic);
  if (!useAtomic)
    k_red<<<(Bc * GR * Hc) / 256, 256, 0, stream>>>(part, agg);
  k_fq<<<100, 256, 0, stream>>>(emb, coords, last, Wg, Wf, Wl, Wv, agg, fq, lastc);
  k_score<<<dim3(SSPLIT, 2, Bc), 512, 0, stream>>>(emb, coords, fq, lastc,
                                                   (const unsigned*)bmq, sums, out);
  k_norm<<<15625, 256, 0, stream>>>(out, sums);
}